// Round 12
// baseline (225.275 us; speedup 1.0000x reference)
//
#include <hip/hip_runtime.h>

namespace {

struct SelState {
    unsigned bufcount;  // number of compacted candidates
    unsigned overflow;  // LDS or buffer overflow -> fallback
    unsigned sel0;      // top-12-bit bin of threshold
    unsigned k1;        // remaining rank within sel0 bin
    unsigned sel1;      // top-24 bits of threshold key
    unsigned k2;        // remaining rank within sel1 bin
};

constexpr int BINS12 = 4096;
constexpr int BINS8  = 256;
constexpr int LCAP   = 1024;       // per-block candidate staging (8 KiB LDS; ~42 sigma above expected 305)
constexpr float GUESS = 2.5f;      // speculative lower bound; f2key(2.5)=0xC0200000 is a 12-bit bin boundary
constexpr unsigned GBIN = 0xC02u;  // top-12 bin of GUESS
constexpr int CBINS = 0x1000 - 0xC02;  // 1022 candidate bins

using f4v = __attribute__((ext_vector_type(4))) float;

// Monotone map: float bits -> unsigned, ascending with float value.
__device__ __forceinline__ unsigned f2key(float f) {
    unsigned u = __float_as_uint(f);
    return (u & 0x80000000u) ? ~u : (u | 0x80000000u);
}
__device__ __forceinline__ float key2f(unsigned k) {
    return __uint_as_float((k & 0x80000000u) ? (k & 0x7fffffffu) : ~k);
}
__device__ __forceinline__ bool is_fb(const SelState* st, unsigned total_k, unsigned force_fb) {
    return force_fb || st->overflow || (st->bufcount < total_k);
}

// Per-block descending-rank scan of a finalized histogram. All blocks compute the
// same result (deterministic). res[0]=bin index, res[1]=remaining rank (1-based).
template <int NB>
__device__ __forceinline__ void scan_desc(const unsigned* __restrict__ hist, unsigned k,
                                          unsigned* __restrict__ lh, unsigned* __restrict__ res) {
    constexpr int CH = NB / 256;
    const int t = threadIdx.x;
    if (t == 0) { res[0] = 0; res[1] = k; }
    unsigned s = 0;
#pragma unroll
    for (int j = 0; j < CH; ++j) {
        unsigned c = hist[NB - 1 - (t * CH + j)];
        lh[t * CH + j] = c;  // descending bin order
        s += c;
    }
    __syncthreads();
    const int lane = t & 63, wid = t >> 6;
    unsigned v = s;
#pragma unroll
    for (int d = 1; d < 64; d <<= 1) {
        unsigned u = __shfl_up(v, (unsigned)d, 64);
        if (lane >= d) v += u;
    }
    __shared__ unsigned wp[4];
    if (lane == 63) wp[wid] = v;
    __syncthreads();
    unsigned add = 0;
    for (int w = 0; w < wid; ++w) add += wp[w];
    v += add;
    unsigned pre = v - s;  // exclusive prefix (descending-rank order)
    if (k > pre && k <= v) {  // exactly one thread (when total >= k)
        unsigned cum = pre;
#pragma unroll
        for (int j = 0; j < CH; ++j) {
            unsigned c = lh[t * CH + j];
            if (cum + c >= k) { res[0] = (unsigned)(NB - 1 - (t * CH + j)); res[1] = k - cum; break; }
            cum += c;
        }
    }
    __syncthreads();
}

// Fused: stream x once -> write out=0 everywhere, compact (key,idx) of candidates
// >= GUESS, and build the candidate-range 12-bit histogram (bins GBIN..0xFFF).
// 2 x float4 per iteration for vmem ILP; 12.2 KiB LDS -> 8 blocks/CU.
__global__ __launch_bounds__(256) void pass1_kernel(const float* __restrict__ x,
                                                    float* __restrict__ out, long long n,
                                                    unsigned* __restrict__ keys,
                                                    unsigned* __restrict__ idxs,
                                                    unsigned bufcap,
                                                    unsigned* __restrict__ hist0s,
                                                    SelState* __restrict__ st,
                                                    unsigned force_fb) {
    if (force_fb) return;  // fallback path rewrites everything later
    __shared__ unsigned lkey[LCAP];
    __shared__ unsigned lidx[LCAP];
    __shared__ unsigned lhist[CBINS];
    __shared__ unsigned lcnt, gbase;
    for (int i = threadIdx.x; i < CBINS; i += 256) lhist[i] = 0;
    if (threadIdx.x == 0) lcnt = 0;
    __syncthreads();

    const unsigned GKEY = f2key(GUESS);
    long long n8 = n >> 3;
    long long tid = (long long)blockIdx.x * blockDim.x + threadIdx.x;
    long long stride = (long long)gridDim.x * blockDim.x;
    const f4v* xv = (const f4v*)x;
    f4v* ov = (f4v*)out;
    f4v z4 = {0.f, 0.f, 0.f, 0.f};

    for (long long i = tid; i < n8; i += stride) {
        f4v a = __builtin_nontemporal_load(&xv[2 * i]);
        f4v b = __builtin_nontemporal_load(&xv[2 * i + 1]);
        __builtin_nontemporal_store(z4, &ov[2 * i]);
        __builtin_nontemporal_store(z4, &ov[2 * i + 1]);
#pragma unroll
        for (int c = 0; c < 4; ++c) {
            unsigned key = f2key(a[c]);
            if (key >= GKEY) {
                unsigned p = atomicAdd(&lcnt, 1u);
                if (p < LCAP) { lkey[p] = key; lidx[p] = (unsigned)((i << 3) + c); }
                atomicAdd(&lhist[(key >> 20) - GBIN], 1u);
            }
        }
#pragma unroll
        for (int c = 0; c < 4; ++c) {
            unsigned key = f2key(b[c]);
            if (key >= GKEY) {
                unsigned p = atomicAdd(&lcnt, 1u);
                if (p < LCAP) { lkey[p] = key; lidx[p] = (unsigned)((i << 3) + 4 + c); }
                atomicAdd(&lhist[(key >> 20) - GBIN], 1u);
            }
        }
    }
    for (long long i = (n8 << 3) + tid; i < n; i += stride) {
        float v = x[i];
        out[i] = 0.f;
        unsigned key = f2key(v);
        if (key >= GKEY) {
            unsigned p = atomicAdd(&lcnt, 1u);
            if (p < LCAP) { lkey[p] = key; lidx[p] = (unsigned)i; }
            atomicAdd(&lhist[(key >> 20) - GBIN], 1u);
        }
    }

    __syncthreads();
    unsigned cnt = lcnt > LCAP ? LCAP : lcnt;
    if (threadIdx.x == 0) {
        if (lcnt > LCAP) atomicOr(&st->overflow, 1u);
        unsigned base = atomicAdd(&st->bufcount, cnt);
        if (base + cnt > bufcap) atomicOr(&st->overflow, 1u);
        gbase = base;
    }
    __syncthreads();
    unsigned base = gbase;
    for (unsigned i = threadIdx.x; i < cnt; i += 256) {
        unsigned dst = base + i;
        if (dst < bufcap) { keys[dst] = lkey[i]; idxs[dst] = lidx[i]; }
    }
    for (int i = threadIdx.x; i < CBINS; i += 256) {
        unsigned c = lhist[i];
        if (c) atomicAdd(&hist0s[GBIN + i], c);
    }
}

// Fallback-only: full 12-bit histogram over x into hist0f. No-op on fast path.
__global__ __launch_bounds__(256) void fbh0_kernel(const float* __restrict__ x, long long n,
                                                   unsigned* __restrict__ hist0f,
                                                   const SelState* __restrict__ st,
                                                   unsigned total_k, unsigned force_fb) {
    if (!is_fb(st, total_k, force_fb)) return;
    __shared__ unsigned lh[BINS12];
    for (int i = threadIdx.x; i < BINS12; i += 256) lh[i] = 0;
    __syncthreads();
    long long n4 = n >> 2;
    long long tid = (long long)blockIdx.x * blockDim.x + threadIdx.x;
    long long stride = (long long)gridDim.x * blockDim.x;
    const float4* x4 = (const float4*)x;
    for (long long i = tid; i < n4; i += stride) {
        float4 v = x4[i];
        float vv[4] = {v.x, v.y, v.z, v.w};
#pragma unroll
        for (int c = 0; c < 4; ++c) atomicAdd(&lh[f2key(vv[c]) >> 20], 1u);
    }
    for (long long i = (n4 << 2) + tid; i < n; i += stride)
        atomicAdd(&lh[f2key(x[i]) >> 20], 1u);
    __syncthreads();
    for (int i = threadIdx.x; i < BINS12; i += 256) {
        unsigned c = lh[i];
        if (c) atomicAdd(&hist0f[i], c);
    }
}

// scan0 (recomputed per block) + hist1 accumulation.
__global__ __launch_bounds__(256) void hist1_kernel(const float* __restrict__ x, long long n,
                                                    const unsigned* __restrict__ keys,
                                                    const unsigned* __restrict__ hist0s,
                                                    const unsigned* __restrict__ hist0f,
                                                    unsigned* __restrict__ hist1,
                                                    SelState* __restrict__ st,
                                                    unsigned total_k, unsigned force_fb) {
    __shared__ unsigned lh[BINS12];
    __shared__ unsigned res[2];
    const bool fb = is_fb(st, total_k, force_fb);
    scan_desc<BINS12>(fb ? hist0f : hist0s, total_k, lh, res);
    const unsigned sel0 = res[0];
    if (threadIdx.x == 0 && blockIdx.x == 0) { st->sel0 = sel0; st->k1 = res[1]; }

    for (int i = threadIdx.x; i < BINS12; i += 256) lh[i] = 0;
    __syncthreads();

    long long tid = (long long)blockIdx.x * blockDim.x + threadIdx.x;
    long long stride = (long long)gridDim.x * blockDim.x;

    if (fb) {
        long long n4 = n >> 2;
        const float4* x4 = (const float4*)x;
        for (long long i = tid; i < n4; i += stride) {
            float4 v = x4[i];
            float vv[4] = {v.x, v.y, v.z, v.w};
#pragma unroll
            for (int c = 0; c < 4; ++c) {
                unsigned key = f2key(vv[c]);
                if ((key >> 20) == sel0) atomicAdd(&lh[(key >> 8) & 0xFFFu], 1u);
            }
        }
        for (long long i = (n4 << 2) + tid; i < n; i += stride) {
            unsigned key = f2key(x[i]);
            if ((key >> 20) == sel0) atomicAdd(&lh[(key >> 8) & 0xFFFu], 1u);
        }
    } else {
        long long cnt = (long long)st->bufcount;
        long long c4 = cnt >> 2;
        const uint4* k4 = (const uint4*)keys;
        for (long long i = tid; i < c4; i += stride) {
            uint4 kv = k4[i];
            unsigned kk[4] = {kv.x, kv.y, kv.z, kv.w};
#pragma unroll
            for (int c = 0; c < 4; ++c)
                if ((kk[c] >> 20) == sel0) atomicAdd(&lh[(kk[c] >> 8) & 0xFFFu], 1u);
        }
        for (long long i = (c4 << 2) + tid; i < cnt; i += stride) {
            unsigned key = keys[i];
            if ((key >> 20) == sel0) atomicAdd(&lh[(key >> 8) & 0xFFFu], 1u);
        }
    }

    __syncthreads();
    for (int i = threadIdx.x; i < BINS12; i += 256) {
        unsigned c = lh[i];
        if (c) atomicAdd(&hist1[i], c);
    }
}

// scan1 (per block, k from st->k1) + hist2 accumulation.
__global__ __launch_bounds__(256) void hist2_kernel(const float* __restrict__ x, long long n,
                                                    const unsigned* __restrict__ keys,
                                                    const unsigned* __restrict__ hist1,
                                                    unsigned* __restrict__ hist2,
                                                    SelState* __restrict__ st,
                                                    unsigned total_k, unsigned force_fb) {
    __shared__ unsigned lh[BINS12];
    __shared__ unsigned res[2];
    scan_desc<BINS12>(hist1, st->k1, lh, res);
    const unsigned sel1 = (st->sel0 << 12) | res[0];  // top-24 bits
    if (threadIdx.x == 0 && blockIdx.x == 0) { st->sel1 = sel1; st->k2 = res[1]; }

    for (int i = threadIdx.x; i < BINS8; i += 256) lh[i] = 0;
    __syncthreads();

    long long tid = (long long)blockIdx.x * blockDim.x + threadIdx.x;
    long long stride = (long long)gridDim.x * blockDim.x;

    if (is_fb(st, total_k, force_fb)) {
        long long n4 = n >> 2;
        const float4* x4 = (const float4*)x;
        for (long long i = tid; i < n4; i += stride) {
            float4 v = x4[i];
            float vv[4] = {v.x, v.y, v.z, v.w};
#pragma unroll
            for (int c = 0; c < 4; ++c) {
                unsigned key = f2key(vv[c]);
                if ((key >> 8) == sel1) atomicAdd(&lh[key & 0xFFu], 1u);
            }
        }
        for (long long i = (n4 << 2) + tid; i < n; i += stride) {
            unsigned key = f2key(x[i]);
            if ((key >> 8) == sel1) atomicAdd(&lh[key & 0xFFu], 1u);
        }
    } else {
        long long cnt = (long long)st->bufcount;
        long long c4 = cnt >> 2;
        const uint4* k4 = (const uint4*)keys;
        for (long long i = tid; i < c4; i += stride) {
            uint4 kv = k4[i];
            unsigned kk[4] = {kv.x, kv.y, kv.z, kv.w};
#pragma unroll
            for (int c = 0; c < 4; ++c)
                if ((kk[c] >> 8) == sel1) atomicAdd(&lh[kk[c] & 0xFFu], 1u);
        }
        for (long long i = (c4 << 2) + tid; i < cnt; i += stride) {
            unsigned key = keys[i];
            if ((key >> 8) == sel1) atomicAdd(&lh[key & 0xFFu], 1u);
        }
    }

    __syncthreads();
    for (int i = threadIdx.x; i < BINS8; i += 256) {
        unsigned c = lh[i];
        if (c) atomicAdd(&hist2[i], c);
    }
}

// scan2 (per block, k from st->k2) -> threshold; compact scatter or fallback full gate.
__global__ __launch_bounds__(256) void gate_kernel(const float* __restrict__ x,
                                                   float* __restrict__ out, long long n,
                                                   const unsigned* __restrict__ keys,
                                                   const unsigned* __restrict__ idxs,
                                                   const unsigned* __restrict__ hist2,
                                                   const SelState* __restrict__ st,
                                                   unsigned total_k, unsigned force_fb) {
    __shared__ unsigned lh[BINS8];
    __shared__ unsigned res[2];
    scan_desc<BINS8>(hist2, st->k2, lh, res);
    const unsigned tkey = (st->sel1 << 8) | res[0];

    long long tid = (long long)blockIdx.x * blockDim.x + threadIdx.x;
    long long stride = (long long)gridDim.x * blockDim.x;

    if (is_fb(st, total_k, force_fb)) {
        float thr = key2f(tkey);
        long long n4 = n >> 2;
        const float4* x4 = (const float4*)x;
        float4* o4 = (float4*)out;
        for (long long i = tid; i < n4; i += stride) {
            float4 v = x4[i];
            float4 r;
            r.x = (v.x >= thr) ? fmaxf(v.x, 0.f) : 0.f;
            r.y = (v.y >= thr) ? fmaxf(v.y, 0.f) : 0.f;
            r.z = (v.z >= thr) ? fmaxf(v.z, 0.f) : 0.f;
            r.w = (v.w >= thr) ? fmaxf(v.w, 0.f) : 0.f;
            o4[i] = r;
        }
        for (long long i = (n4 << 2) + tid; i < n; i += stride) {
            float v = x[i];
            out[i] = (v >= thr) ? fmaxf(v, 0.f) : 0.f;
        }
    } else {
        // Non-candidates were zeroed by pass1. thr >= GUESS > 0 so relu(x)=x here.
        long long cnt = (long long)st->bufcount;
        for (long long i = tid; i < cnt; i += stride) {
            unsigned kk = keys[i];
            if (kk >= tkey) out[idxs[i]] = key2f(kk);
        }
    }
}

}  // namespace

extern "C" void kernel_launch(void* const* d_in, const int* in_sizes, int n_in,
                              void* d_out, int out_size, void* d_ws, size_t ws_size,
                              hipStream_t stream) {
    const float* x = (const float*)d_in[0];
    float* out = (float*)d_out;
    long long n = (long long)in_sizes[0];

    long long tk = 64LL * 4096LL;
    if (tk > n) tk = n;
    unsigned total_k = (unsigned)tk;

    char* ws = (char*)d_ws;
    unsigned* hist0s = (unsigned*)(ws);            // 16 KiB (speculative, candidates)
    unsigned* hist0f = (unsigned*)(ws + 16384);    // 16 KiB (fallback, full x)
    unsigned* hist1  = (unsigned*)(ws + 32768);    // 16 KiB
    unsigned* hist2  = (unsigned*)(ws + 49152);    // 1 KiB
    SelState* st     = (SelState*)(ws + 50176);

    unsigned bufcap = 0;
    unsigned* keys = (unsigned*)(ws + 65536);
    unsigned* idxs = nullptr;
    if (ws_size > 65536) {
        size_t avail = (ws_size - 65536) / 8;  // two u32 arrays
        size_t cap = avail > 16u * 1024u * 1024u ? 16u * 1024u * 1024u : avail;
        bufcap = (unsigned)(cap & ~3ull);
        idxs = keys + bufcap;
    }
    unsigned force_fb = (bufcap < 2u * total_k || n > 0xFFFF0000LL) ? 1u : 0u;

    const int blocks = 2048;

    // Zero hists + state in one small memset (replaces init_kernel).
    hipMemsetAsync(ws, 0, 50176 + sizeof(SelState), stream);
    pass1_kernel<<<blocks, 256, 0, stream>>>(x, out, n, keys, idxs, bufcap, hist0s, st, force_fb);
    fbh0_kernel<<<blocks, 256, 0, stream>>>(x, n, hist0f, st, total_k, force_fb);
    hist1_kernel<<<blocks, 256, 0, stream>>>(x, n, keys, hist0s, hist0f, hist1, st, total_k, force_fb);
    hist2_kernel<<<blocks, 256, 0, stream>>>(x, n, keys, hist1, hist2, st, total_k, force_fb);
    gate_kernel<<<blocks, 256, 0, stream>>>(x, out, n, keys, idxs, hist2, st, total_k, force_fb);
}

// Round 13
// 200.857 us; speedup vs baseline: 1.1216x; 1.1216x over previous
//
#include <hip/hip_runtime.h>

namespace {

struct SelState {
    unsigned bufcount;  // number of compacted candidates
    unsigned overflow;  // LDS or buffer overflow -> fallback
    unsigned sel0;      // top-12-bit bin of threshold
    unsigned k1;        // remaining rank within sel0 bin
    unsigned sel1;      // top-24 bits of threshold key
    unsigned k2;        // remaining rank within sel1 bin
};

constexpr int BINS12 = 4096;
constexpr int BINS8  = 256;
constexpr int LCAP   = 2048;       // per-block candidate staging (16 KiB LDS)
constexpr float GUESS = 2.5f;      // speculative lower bound; f2key(2.5)=0xC0200000 is a 12-bit bin boundary
constexpr unsigned GBIN = 0xC02u;  // top-12 bin of GUESS
constexpr int CBINS = 0x1000 - 0xC02;  // 1022 candidate bins

using f4v = __attribute__((ext_vector_type(4))) float;

// Monotone map: float bits -> unsigned, ascending with float value.
__device__ __forceinline__ unsigned f2key(float f) {
    unsigned u = __float_as_uint(f);
    return (u & 0x80000000u) ? ~u : (u | 0x80000000u);
}
__device__ __forceinline__ float key2f(unsigned k) {
    return __uint_as_float((k & 0x80000000u) ? (k & 0x7fffffffu) : ~k);
}
__device__ __forceinline__ bool is_fb(const SelState* st, unsigned total_k, unsigned force_fb) {
    return force_fb || st->overflow || (st->bufcount < total_k);
}

// Per-block descending-rank scan of a finalized histogram. All blocks compute the
// same result (deterministic). res[0]=bin index, res[1]=remaining rank (1-based).
template <int NB>
__device__ __forceinline__ void scan_desc(const unsigned* __restrict__ hist, unsigned k,
                                          unsigned* __restrict__ lh, unsigned* __restrict__ res) {
    constexpr int CH = NB / 256;
    const int t = threadIdx.x;
    if (t == 0) { res[0] = 0; res[1] = k; }
    unsigned s = 0;
#pragma unroll
    for (int j = 0; j < CH; ++j) {
        unsigned c = hist[NB - 1 - (t * CH + j)];
        lh[t * CH + j] = c;  // descending bin order
        s += c;
    }
    __syncthreads();
    const int lane = t & 63, wid = t >> 6;
    unsigned v = s;
#pragma unroll
    for (int d = 1; d < 64; d <<= 1) {
        unsigned u = __shfl_up(v, (unsigned)d, 64);
        if (lane >= d) v += u;
    }
    __shared__ unsigned wp[4];
    if (lane == 63) wp[wid] = v;
    __syncthreads();
    unsigned add = 0;
    for (int w = 0; w < wid; ++w) add += wp[w];
    v += add;
    unsigned pre = v - s;  // exclusive prefix (descending-rank order)
    if (k > pre && k <= v) {  // exactly one thread (when total >= k)
        unsigned cum = pre;
#pragma unroll
        for (int j = 0; j < CH; ++j) {
            unsigned c = lh[t * CH + j];
            if (cum + c >= k) { res[0] = (unsigned)(NB - 1 - (t * CH + j)); res[1] = k - cum; break; }
            cum += c;
        }
    }
    __syncthreads();
}

// Fused: stream x once -> write out=0 everywhere, compact (key,idx) of candidates
// >= GUESS, and build the candidate-range 12-bit histogram (bins GBIN..0xFFF).
__global__ __launch_bounds__(256) void pass1_kernel(const float* __restrict__ x,
                                                    float* __restrict__ out, long long n,
                                                    unsigned* __restrict__ keys,
                                                    unsigned* __restrict__ idxs,
                                                    unsigned bufcap,
                                                    unsigned* __restrict__ hist0s,
                                                    SelState* __restrict__ st,
                                                    unsigned force_fb) {
    if (force_fb) return;  // fallback path rewrites everything later
    __shared__ unsigned lkey[LCAP];
    __shared__ unsigned lidx[LCAP];
    __shared__ unsigned lhist[CBINS];
    __shared__ unsigned lcnt, gbase;
    for (int i = threadIdx.x; i < CBINS; i += 256) lhist[i] = 0;
    if (threadIdx.x == 0) lcnt = 0;
    __syncthreads();

    const unsigned GKEY = f2key(GUESS);
    long long n4 = n >> 2;
    long long tid = (long long)blockIdx.x * blockDim.x + threadIdx.x;
    long long stride = (long long)gridDim.x * blockDim.x;
    const f4v* xv = (const f4v*)x;
    f4v* ov = (f4v*)out;
    f4v z4 = {0.f, 0.f, 0.f, 0.f};

    for (long long i = tid; i < n4; i += stride) {
        f4v v = __builtin_nontemporal_load(&xv[i]);
        __builtin_nontemporal_store(z4, &ov[i]);
#pragma unroll
        for (int c = 0; c < 4; ++c) {
            unsigned key = f2key(v[c]);
            if (key >= GKEY) {
                unsigned p = atomicAdd(&lcnt, 1u);
                if (p < LCAP) { lkey[p] = key; lidx[p] = (unsigned)((i << 2) + c); }
                atomicAdd(&lhist[(key >> 20) - GBIN], 1u);
            }
        }
    }
    for (long long i = (n4 << 2) + tid; i < n; i += stride) {
        float v = x[i];
        out[i] = 0.f;
        unsigned key = f2key(v);
        if (key >= GKEY) {
            unsigned p = atomicAdd(&lcnt, 1u);
            if (p < LCAP) { lkey[p] = key; lidx[p] = (unsigned)i; }
            atomicAdd(&lhist[(key >> 20) - GBIN], 1u);
        }
    }

    __syncthreads();
    unsigned cnt = lcnt > LCAP ? LCAP : lcnt;
    if (threadIdx.x == 0) {
        if (lcnt > LCAP) atomicOr(&st->overflow, 1u);
        unsigned base = atomicAdd(&st->bufcount, cnt);
        if (base + cnt > bufcap) atomicOr(&st->overflow, 1u);
        gbase = base;
    }
    __syncthreads();
    unsigned base = gbase;
    for (unsigned i = threadIdx.x; i < cnt; i += 256) {
        unsigned dst = base + i;
        if (dst < bufcap) { keys[dst] = lkey[i]; idxs[dst] = lidx[i]; }
    }
    for (int i = threadIdx.x; i < CBINS; i += 256) {
        unsigned c = lhist[i];
        if (c) atomicAdd(&hist0s[GBIN + i], c);
    }
}

// Fallback-only: full 12-bit histogram over x into hist0f. No-op on fast path.
__global__ __launch_bounds__(256) void fbh0_kernel(const float* __restrict__ x, long long n,
                                                   unsigned* __restrict__ hist0f,
                                                   const SelState* __restrict__ st,
                                                   unsigned total_k, unsigned force_fb) {
    if (!is_fb(st, total_k, force_fb)) return;
    __shared__ unsigned lh[BINS12];
    for (int i = threadIdx.x; i < BINS12; i += 256) lh[i] = 0;
    __syncthreads();
    long long n4 = n >> 2;
    long long tid = (long long)blockIdx.x * blockDim.x + threadIdx.x;
    long long stride = (long long)gridDim.x * blockDim.x;
    const float4* x4 = (const float4*)x;
    for (long long i = tid; i < n4; i += stride) {
        float4 v = x4[i];
        float vv[4] = {v.x, v.y, v.z, v.w};
#pragma unroll
        for (int c = 0; c < 4; ++c) atomicAdd(&lh[f2key(vv[c]) >> 20], 1u);
    }
    for (long long i = (n4 << 2) + tid; i < n; i += stride)
        atomicAdd(&lh[f2key(x[i]) >> 20], 1u);
    __syncthreads();
    for (int i = threadIdx.x; i < BINS12; i += 256) {
        unsigned c = lh[i];
        if (c) atomicAdd(&hist0f[i], c);
    }
}

// scan0 (recomputed per block) + hist1 accumulation.
__global__ __launch_bounds__(256) void hist1_kernel(const float* __restrict__ x, long long n,
                                                    const unsigned* __restrict__ keys,
                                                    const unsigned* __restrict__ hist0s,
                                                    const unsigned* __restrict__ hist0f,
                                                    unsigned* __restrict__ hist1,
                                                    SelState* __restrict__ st,
                                                    unsigned total_k, unsigned force_fb) {
    __shared__ unsigned lh[BINS12];
    __shared__ unsigned res[2];
    const bool fb = is_fb(st, total_k, force_fb);
    scan_desc<BINS12>(fb ? hist0f : hist0s, total_k, lh, res);
    const unsigned sel0 = res[0];
    if (threadIdx.x == 0 && blockIdx.x == 0) { st->sel0 = sel0; st->k1 = res[1]; }

    for (int i = threadIdx.x; i < BINS12; i += 256) lh[i] = 0;
    __syncthreads();

    long long tid = (long long)blockIdx.x * blockDim.x + threadIdx.x;
    long long stride = (long long)gridDim.x * blockDim.x;

    if (fb) {
        long long n4 = n >> 2;
        const float4* x4 = (const float4*)x;
        for (long long i = tid; i < n4; i += stride) {
            float4 v = x4[i];
            float vv[4] = {v.x, v.y, v.z, v.w};
#pragma unroll
            for (int c = 0; c < 4; ++c) {
                unsigned key = f2key(vv[c]);
                if ((key >> 20) == sel0) atomicAdd(&lh[(key >> 8) & 0xFFFu], 1u);
            }
        }
        for (long long i = (n4 << 2) + tid; i < n; i += stride) {
            unsigned key = f2key(x[i]);
            if ((key >> 20) == sel0) atomicAdd(&lh[(key >> 8) & 0xFFFu], 1u);
        }
    } else {
        long long cnt = (long long)st->bufcount;
        long long c4 = cnt >> 2;
        const uint4* k4 = (const uint4*)keys;
        for (long long i = tid; i < c4; i += stride) {
            uint4 kv = k4[i];
            unsigned kk[4] = {kv.x, kv.y, kv.z, kv.w};
#pragma unroll
            for (int c = 0; c < 4; ++c)
                if ((kk[c] >> 20) == sel0) atomicAdd(&lh[(kk[c] >> 8) & 0xFFFu], 1u);
        }
        for (long long i = (c4 << 2) + tid; i < cnt; i += stride) {
            unsigned key = keys[i];
            if ((key >> 20) == sel0) atomicAdd(&lh[(key >> 8) & 0xFFFu], 1u);
        }
    }

    __syncthreads();
    for (int i = threadIdx.x; i < BINS12; i += 256) {
        unsigned c = lh[i];
        if (c) atomicAdd(&hist1[i], c);
    }
}

// scan1 (per block, k from st->k1) + hist2 accumulation.
__global__ __launch_bounds__(256) void hist2_kernel(const float* __restrict__ x, long long n,
                                                    const unsigned* __restrict__ keys,
                                                    const unsigned* __restrict__ hist1,
                                                    unsigned* __restrict__ hist2,
                                                    SelState* __restrict__ st,
                                                    unsigned total_k, unsigned force_fb) {
    __shared__ unsigned lh[BINS12];
    __shared__ unsigned res[2];
    scan_desc<BINS12>(hist1, st->k1, lh, res);
    const unsigned sel1 = (st->sel0 << 12) | res[0];  // top-24 bits
    if (threadIdx.x == 0 && blockIdx.x == 0) { st->sel1 = sel1; st->k2 = res[1]; }

    for (int i = threadIdx.x; i < BINS8; i += 256) lh[i] = 0;
    __syncthreads();

    long long tid = (long long)blockIdx.x * blockDim.x + threadIdx.x;
    long long stride = (long long)gridDim.x * blockDim.x;

    if (is_fb(st, total_k, force_fb)) {
        long long n4 = n >> 2;
        const float4* x4 = (const float4*)x;
        for (long long i = tid; i < n4; i += stride) {
            float4 v = x4[i];
            float vv[4] = {v.x, v.y, v.z, v.w};
#pragma unroll
            for (int c = 0; c < 4; ++c) {
                unsigned key = f2key(vv[c]);
                if ((key >> 8) == sel1) atomicAdd(&lh[key & 0xFFu], 1u);
            }
        }
        for (long long i = (n4 << 2) + tid; i < n; i += stride) {
            unsigned key = f2key(x[i]);
            if ((key >> 8) == sel1) atomicAdd(&lh[key & 0xFFu], 1u);
        }
    } else {
        long long cnt = (long long)st->bufcount;
        long long c4 = cnt >> 2;
        const uint4* k4 = (const uint4*)keys;
        for (long long i = tid; i < c4; i += stride) {
            uint4 kv = k4[i];
            unsigned kk[4] = {kv.x, kv.y, kv.z, kv.w};
#pragma unroll
            for (int c = 0; c < 4; ++c)
                if ((kk[c] >> 8) == sel1) atomicAdd(&lh[kk[c] & 0xFFu], 1u);
        }
        for (long long i = (c4 << 2) + tid; i < cnt; i += stride) {
            unsigned key = keys[i];
            if ((key >> 8) == sel1) atomicAdd(&lh[key & 0xFFu], 1u);
        }
    }

    __syncthreads();
    for (int i = threadIdx.x; i < BINS8; i += 256) {
        unsigned c = lh[i];
        if (c) atomicAdd(&hist2[i], c);
    }
}

// scan2 (per block, k from st->k2) -> threshold; compact scatter or fallback full gate.
__global__ __launch_bounds__(256) void gate_kernel(const float* __restrict__ x,
                                                   float* __restrict__ out, long long n,
                                                   const unsigned* __restrict__ keys,
                                                   const unsigned* __restrict__ idxs,
                                                   const unsigned* __restrict__ hist2,
                                                   const SelState* __restrict__ st,
                                                   unsigned total_k, unsigned force_fb) {
    __shared__ unsigned lh[BINS8];
    __shared__ unsigned res[2];
    scan_desc<BINS8>(hist2, st->k2, lh, res);
    const unsigned tkey = (st->sel1 << 8) | res[0];

    long long tid = (long long)blockIdx.x * blockDim.x + threadIdx.x;
    long long stride = (long long)gridDim.x * blockDim.x;

    if (is_fb(st, total_k, force_fb)) {
        float thr = key2f(tkey);
        long long n4 = n >> 2;
        const float4* x4 = (const float4*)x;
        float4* o4 = (float4*)out;
        for (long long i = tid; i < n4; i += stride) {
            float4 v = x4[i];
            float4 r;
            r.x = (v.x >= thr) ? fmaxf(v.x, 0.f) : 0.f;
            r.y = (v.y >= thr) ? fmaxf(v.y, 0.f) : 0.f;
            r.z = (v.z >= thr) ? fmaxf(v.z, 0.f) : 0.f;
            r.w = (v.w >= thr) ? fmaxf(v.w, 0.f) : 0.f;
            o4[i] = r;
        }
        for (long long i = (n4 << 2) + tid; i < n; i += stride) {
            float v = x[i];
            out[i] = (v >= thr) ? fmaxf(v, 0.f) : 0.f;
        }
    } else {
        // Non-candidates were zeroed by pass1. thr >= GUESS > 0 so relu(x)=x here.
        long long cnt = (long long)st->bufcount;
        for (long long i = tid; i < cnt; i += stride) {
            unsigned kk = keys[i];
            if (kk >= tkey) out[idxs[i]] = key2f(kk);
        }
    }
}

}  // namespace

extern "C" void kernel_launch(void* const* d_in, const int* in_sizes, int n_in,
                              void* d_out, int out_size, void* d_ws, size_t ws_size,
                              hipStream_t stream) {
    const float* x = (const float*)d_in[0];
    float* out = (float*)d_out;
    long long n = (long long)in_sizes[0];

    long long tk = 64LL * 4096LL;
    if (tk > n) tk = n;
    unsigned total_k = (unsigned)tk;

    char* ws = (char*)d_ws;
    unsigned* hist0s = (unsigned*)(ws);            // 16 KiB (speculative, candidates)
    unsigned* hist0f = (unsigned*)(ws + 16384);    // 16 KiB (fallback, full x)
    unsigned* hist1  = (unsigned*)(ws + 32768);    // 16 KiB
    unsigned* hist2  = (unsigned*)(ws + 49152);    // 1 KiB
    SelState* st     = (SelState*)(ws + 50176);

    unsigned bufcap = 0;
    unsigned* keys = (unsigned*)(ws + 65536);
    unsigned* idxs = nullptr;
    if (ws_size > 65536) {
        size_t avail = (ws_size - 65536) / 8;  // two u32 arrays
        size_t cap = avail > 16u * 1024u * 1024u ? 16u * 1024u * 1024u : avail;
        bufcap = (unsigned)(cap & ~3ull);
        idxs = keys + bufcap;
    }
    unsigned force_fb = (bufcap < 2u * total_k || n > 0xFFFF0000LL) ? 1u : 0u;

    const int blocks = 2048;

    // Zero hists + state in one small memset (replaces init_kernel).
    hipMemsetAsync(ws, 0, 50176 + sizeof(SelState), stream);
    pass1_kernel<<<blocks, 256, 0, stream>>>(x, out, n, keys, idxs, bufcap, hist0s, st, force_fb);
    fbh0_kernel<<<blocks, 256, 0, stream>>>(x, n, hist0f, st, total_k, force_fb);
    hist1_kernel<<<blocks, 256, 0, stream>>>(x, n, keys, hist0s, hist0f, hist1, st, total_k, force_fb);
    hist2_kernel<<<blocks, 256, 0, stream>>>(x, n, keys, hist1, hist2, st, total_k, force_fb);
    gate_kernel<<<blocks, 256, 0, stream>>>(x, out, n, keys, idxs, hist2, st, total_k, force_fb);
}